// Round 12
// baseline (301.632 us; speedup 1.0000x reference)
//
#include <hip/hip_runtime.h>
#include <math.h>

#define NTHR 256
#define WAVES_PER_BLOCK 4
#define NBLOCKS 1536   // 6 blocks/CU on 256 CUs; with VGPR<=85 all co-resident in one round

typedef __attribute__((ext_vector_type(8))) _Float16 f16x8;   // MFMA A/B frag (4 VGPRs)
typedef __attribute__((ext_vector_type(2))) _Float16 half2v;
typedef __attribute__((ext_vector_type(4))) float f32x4;      // MFMA C/D frag
typedef __attribute__((ext_vector_type(4))) unsigned uint4v;

#define CEXP 28.85390082f     // 20 * log2(e)
#define KLOG 0.03465735903f   // ln(2) / 20

// raw gfx950 transcendentals: v_exp_f32 is 2^x, v_log_f32 is log2(x)
#define EXP2F(v) __builtin_amdgcn_exp2f(v)
#define LOG2F(v) __builtin_amdgcn_logf(v)

// softplus(beta=20): h = max(z,0) + KLOG*l, l = log2(1+2^(-|CEXP z|))
// s = sigmoid(20z) = 1 - 2^(-CEXP*h)  [exact identity, select-free]
static __device__ __forceinline__ float act_hs(float z, float& s) {
    float cz = CEXP * z;
    float e  = EXP2F(-fabsf(cz));
    float l  = LOG2F(1.0f + e);
    float zp = fmaxf(z, 0.0f);
    s = 1.0f - EXP2F(fmaf(-CEXP, zp, -l));
    return fmaf(KLOG, l, zp);
}
// select-free: exp2 overflow->inf, rcp(inf)->0 saturates correctly
static __device__ __forceinline__ float sigmoid20(float z) {
    float e = EXP2F(-CEXP * z);
    return __builtin_amdgcn_rcpf(1.0f + e);
}

// pack 2 floats -> 2 f16 in one v_cvt_pkrtz_f16_f32
static __device__ __forceinline__ unsigned pk(float a, float b) {
    return __builtin_bit_cast(unsigned, __builtin_amdgcn_cvt_pkrtz(a, b));
}

// tangent stream: single-f16 pack, 4 instr per 8 elements
static __device__ __forceinline__ f16x8 pack8(const float* v) {
    uint4v u = {pk(v[0], v[1]), pk(v[2], v[3]), pk(v[4], v[5]), pk(v[6], v[7])};
    return __builtin_bit_cast(f16x8, u);
}
// forward stream: f16 hi/lo split (residual ~2^-22)
static __device__ __forceinline__ void fsplit8(const float* v, f16x8& hi, f16x8& lo) {
    unsigned h[4], l[4];
    #pragma unroll
    for (int p = 0; p < 4; ++p) {
        float a = v[2 * p], b = v[2 * p + 1];
        unsigned hp = pk(a, b);
        half2v hh = __builtin_bit_cast(half2v, hp);
        h[p] = hp;
        l[p] = pk(a - (float)hh[0], b - (float)hh[1]);
    }
    hi = __builtin_bit_cast(f16x8, (uint4v){h[0], h[1], h[2], h[3]});
    lo = __builtin_bit_cast(f16x8, (uint4v){l[0], l[1], l[2], l[3]});
}

// C-frag pair -> layer-3 B operand (valid via the K-permuted layer-3 A-frag:
// f(g,j) = j<4 ? 4g+j : 16+4g+(j-4)).
static __device__ __forceinline__ void fsplit_cc(const f32x4& c0, const f32x4& c1,
                                                 f16x8& hi, f16x8& lo) {
    float v[8] = {c0[0], c0[1], c0[2], c0[3], c1[0], c1[1], c1[2], c1[3]};
    fsplit8(v, hi, lo);
}
static __device__ __forceinline__ f16x8 pack_cc(const f32x4& c0, const f32x4& c1) {
    uint4v u = {pk(c0[0], c0[1]), pk(c0[2], c0[3]), pk(c1[0], c1[1]), pk(c1[2], c1[3])};
    return __builtin_bit_cast(f16x8, u);
}

// forward, single-f16 weight: D += W*Bh + W*Bl
static __device__ __forceinline__ f32x4 mfma2f(f16x8 w, f16x8 bh, f16x8 bl, f32x4 c) {
    c = __builtin_amdgcn_mfma_f32_16x16x32_f16(w, bh, c, 0, 0, 0);
    c = __builtin_amdgcn_mfma_f32_16x16x32_f16(w, bl, c, 0, 0, 0);
    return c;
}
// tangent, single-f16 both sides: one MFMA
static __device__ __forceinline__ f32x4 mfma1t(f16x8 w, f16x8 b, f32x4 c) {
    return __builtin_amdgcn_mfma_f32_16x16x32_f16(w, b, c, 0, 0, 0);
}

__global__ void __launch_bounds__(NTHR, 6)   // VGPR cap 85; body needs 84 (R10) -> free
presdiv_kernel(const float* __restrict__ x,
               const float* __restrict__ W1, const float* __restrict__ b1,
               const float* __restrict__ W2, const float* __restrict__ b2,
               const float* __restrict__ W3, const float* __restrict__ b3,
               const float* __restrict__ W4,
               float* __restrict__ out, int N)
{
    const int lane = threadIdx.x & 63;
    const int wid  = threadIdx.x >> 6;
    const int n16  = lane & 15;        // sample-within-tile / MFMA col
    const int g    = lane >> 4;        // quad

    // ---- persistent weights (per lane), single f16 (RTN) ----
    f16x8 w2[2], w3[2];
    #pragma unroll
    for (int h = 0; h < 2; ++h) {
        #pragma unroll
        for (int j = 0; j < 8; ++j) {
            const int k2 = g * 8 + j;
            w2[h][j] = (_Float16)W2[k2 * 32 + 16 * h + n16];
            const int k3 = (j < 4) ? (4 * g + j) : (16 + 4 * g + (j - 4));
            w3[h][j] = (_Float16)W3[k3 * 32 + 16 * h + n16];
        }
    }
    float w1r[3][8], bb1[8];
    #pragma unroll
    for (int j = 0; j < 8; ++j) {
        bb1[j] = b1[g * 8 + j];
        #pragma unroll
        for (int d = 0; d < 3; ++d) w1r[d][j] = W1[d * 32 + g * 8 + j];
    }
    float bb2[2][4], bb3[2][4], w4r[2][4][3];
    #pragma unroll
    for (int h = 0; h < 2; ++h)
        #pragma unroll
        for (int r = 0; r < 4; ++r) {
            const int row = 16 * h + 4 * g + r;
            bb2[h][r] = b2[row];
            bb3[h][r] = b3[row];
            #pragma unroll
            for (int k = 0; k < 3; ++k) w4r[h][r][k] = W4[row * 3 + k];
        }

    const int ntiles = (N + 15) >> 4;
    const int nwaves = NBLOCKS * WAVES_PER_BLOCK;
    const f32x4 vzero = {0.f, 0.f, 0.f, 0.f};

    for (int tile = blockIdx.x * WAVES_PER_BLOCK + wid; tile < ntiles; tile += nwaves) {
        int s = tile * 16 + n16;
        if (s >= N) s = N - 1;
        const float x0 = x[3 * s + 0];
        const float x1 = x[3 * s + 1];
        const float x2 = x[3 * s + 2];

        // ---- layer 1 (exact fp32), directly in B-layout ----
        float vF[8], v0[8], v1[8], v2[8];
        #pragma unroll
        for (int j = 0; j < 8; ++j) {
            float z = bb1[j];
            z = fmaf(x0, w1r[0][j], z);
            z = fmaf(x1, w1r[1][j], z);
            z = fmaf(x2, w1r[2][j], z);
            float sg; vF[j] = act_hs(z, sg);
            v0[j] = sg * w1r[0][j];
            v1[j] = sg * w1r[1][j];
            v2[j] = sg * w1r[2][j];
        }

        // ---- layer 2 ----
        f32x4 aF[2], a0[2], a1[2], a2[2];
        aF[0] = (f32x4){bb2[0][0], bb2[0][1], bb2[0][2], bb2[0][3]};
        aF[1] = (f32x4){bb2[1][0], bb2[1][1], bb2[1][2], bb2[1][3]};
        a0[0] = a0[1] = a1[0] = a1[1] = a2[0] = a2[1] = vzero;

        f16x8 bh, bl;
        fsplit8(vF, bh, bl);                 // forward B: full split
        aF[0] = mfma2f(w2[0], bh, bl, aF[0]);
        aF[1] = mfma2f(w2[1], bh, bl, aF[1]);
        f16x8 tb = pack8(v0);                // tangents: single f16
        a0[0] = mfma1t(w2[0], tb, a0[0]);
        a0[1] = mfma1t(w2[1], tb, a0[1]);
        tb = pack8(v1);
        a1[0] = mfma1t(w2[0], tb, a1[0]);
        a1[1] = mfma1t(w2[1], tb, a1[1]);
        tb = pack8(v2);
        a2[0] = mfma1t(w2[0], tb, a2[0]);
        a2[1] = mfma1t(w2[1], tb, a2[1]);

        // ---- boundary: act + diag-scale, in C-layout ----
        #pragma unroll
        for (int h = 0; h < 2; ++h)
            #pragma unroll
            for (int r = 0; r < 4; ++r) {
                float s2v;
                aF[h][r] = act_hs(aF[h][r], s2v);   // h2
                a0[h][r] *= s2v;
                a1[h][r] *= s2v;
                a2[h][r] *= s2v;
            }

        // ---- layer 3: C-frags feed B directly (K-permuted weights) ----
        f32x4 zF[2], u0[2], u1[2], u2[2];
        zF[0] = (f32x4){bb3[0][0], bb3[0][1], bb3[0][2], bb3[0][3]};
        zF[1] = (f32x4){bb3[1][0], bb3[1][1], bb3[1][2], bb3[1][3]};
        u0[0] = u0[1] = u1[0] = u1[1] = u2[0] = u2[1] = vzero;

        fsplit_cc(aF[0], aF[1], bh, bl);
        zF[0] = mfma2f(w3[0], bh, bl, zF[0]);
        zF[1] = mfma2f(w3[1], bh, bl, zF[1]);
        tb = pack_cc(a0[0], a0[1]);
        u0[0] = mfma1t(w3[0], tb, u0[0]);
        u0[1] = mfma1t(w3[1], tb, u0[1]);
        tb = pack_cc(a1[0], a1[1]);
        u1[0] = mfma1t(w3[0], tb, u1[0]);
        u1[1] = mfma1t(w3[1], tb, u1[1]);
        tb = pack_cc(a2[0], a2[1]);
        u2[0] = mfma1t(w3[0], tb, u2[0]);
        u2[1] = mfma1t(w3[1], tb, u2[1]);

        // ---- layer 4 fused with trace combine (6 FMA/row) ----
        float o0 = 0.f, o1 = 0.f, o2 = 0.f;
        #pragma unroll
        for (int h = 0; h < 2; ++h)
            #pragma unroll
            for (int r = 0; r < 4; ++r) {
                const float s3v = sigmoid20(zF[h][r]);
                const float t0v = s3v * u0[h][r];
                const float t1v = s3v * u1[h][r];
                const float t2v = s3v * u2[h][r];
                const float w0 = w4r[h][r][0], w1 = w4r[h][r][1], w2c = w4r[h][r][2];
                o0 = fmaf(t1v, w0, fmaf(t2v, w1, o0));
                o1 = fmaf(-t0v, w0, fmaf(t2v, w2c, o1));
                o2 = fmaf(-t0v, w1, fmaf(-t1v, w2c, o2));
            }

        o0 += __shfl_xor(o0, 16); o0 += __shfl_xor(o0, 32);
        o1 += __shfl_xor(o1, 16); o1 += __shfl_xor(o1, 32);
        o2 += __shfl_xor(o2, 16); o2 += __shfl_xor(o2, 32);

        if (g == 0) {
            out[3 * s + 0] = o0;
            out[3 * s + 1] = o1;
            out[3 * s + 2] = o2;
        }
    }
}

extern "C" void kernel_launch(void* const* d_in, const int* in_sizes, int n_in,
                              void* d_out, int out_size, void* d_ws, size_t ws_size,
                              hipStream_t stream)
{
    const float* x  = (const float*)d_in[0];
    const float* W1 = (const float*)d_in[1];
    const float* b1 = (const float*)d_in[2];
    const float* W2 = (const float*)d_in[3];
    const float* b2 = (const float*)d_in[4];
    const float* W3 = (const float*)d_in[5];
    const float* b3 = (const float*)d_in[6];
    const float* W4 = (const float*)d_in[7];
    // d_in[8] = b4 unused: constant offset cancels in the Jacobian.
    float* out = (float*)d_out;

    const int N = in_sizes[0] / 3;
    presdiv_kernel<<<NBLOCKS, NTHR, 0, stream>>>(x, W1, b1, W2, b2, W3, b3, W4, out, N);
}

// Round 13
// 135.719 us; speedup vs baseline: 2.2225x; 2.2225x over previous
//
#include <hip/hip_runtime.h>
#include <math.h>

#define NTHR 256
#define WAVES_PER_BLOCK 4

typedef __attribute__((ext_vector_type(8))) _Float16 f16x8;   // MFMA A/B frag (4 VGPRs)
typedef __attribute__((ext_vector_type(2))) _Float16 half2v;
typedef __attribute__((ext_vector_type(4))) float f32x4;      // MFMA C/D frag + packed math
typedef __attribute__((ext_vector_type(4))) unsigned uint4v;

#define CEXP 28.85390082f     // 20 * log2(e)
#define KLOG 0.03465735903f   // ln(2) / 20

// raw gfx950 transcendentals: v_exp_f32 is 2^x, v_log_f32 is log2(x)
#define EXP2F(v) __builtin_amdgcn_exp2f(v)
#define LOG2F(v) __builtin_amdgcn_logf(v)

static __device__ __forceinline__ f32x4 splat4(float v) { return (f32x4){v, v, v, v}; }

// Vectorized softplus(beta=20) + derivative: non-transcendental arithmetic on
// f32x4 (compiler forms v_pk_*_f32), scalar loop only for exp2/log2.
// h = max(z,0) + KLOG*l, l = log2(1+2^(-|CEXP z|)); s = 1 - 2^(-CEXP*max(z,0) - l)
static __device__ __forceinline__ void act_hs4(f32x4 z, f32x4& h, f32x4& s) {
    f32x4 az = __builtin_elementwise_abs(splat4(CEXP) * z);
    f32x4 e;
    #pragma unroll
    for (int i = 0; i < 4; ++i) e[i] = EXP2F(-az[i]);
    f32x4 p = splat4(1.0f) + e;
    f32x4 l;
    #pragma unroll
    for (int i = 0; i < 4; ++i) l[i] = LOG2F(p[i]);
    f32x4 zp = __builtin_elementwise_max(z, splat4(0.0f));
    f32x4 q  = __builtin_elementwise_fma(splat4(-CEXP), zp, -l);
    f32x4 t;
    #pragma unroll
    for (int i = 0; i < 4; ++i) t[i] = EXP2F(q[i]);
    s = splat4(1.0f) - t;
    h = __builtin_elementwise_fma(splat4(KLOG), l, zp);
}

// sigmoid(20z) vectorized; select-free (exp2 overflow->inf, rcp(inf)->0)
static __device__ __forceinline__ f32x4 sigmoid4(f32x4 z) {
    f32x4 cz = splat4(-CEXP) * z;
    f32x4 e;
    #pragma unroll
    for (int i = 0; i < 4; ++i) e[i] = EXP2F(cz[i]);
    f32x4 p = splat4(1.0f) + e;
    f32x4 r;
    #pragma unroll
    for (int i = 0; i < 4; ++i) r[i] = __builtin_amdgcn_rcpf(p[i]);
    return r;
}

// pack 2 floats -> 2 f16 in one v_cvt_pkrtz_f16_f32
static __device__ __forceinline__ unsigned pk(float a, float b) {
    return __builtin_bit_cast(unsigned, __builtin_amdgcn_cvt_pkrtz(a, b));
}

// two f32x4 chunks -> single-f16 B operand (tangent streams)
static __device__ __forceinline__ f16x8 pack8v(const f32x4& a, const f32x4& b) {
    uint4v u = {pk(a[0], a[1]), pk(a[2], a[3]), pk(b[0], b[1]), pk(b[2], b[3])};
    return __builtin_bit_cast(f16x8, u);
}
// two f32x4 chunks -> f16 hi/lo split B operand (forward stream, residual ~2^-22)
static __device__ __forceinline__ void fsplit8v(const f32x4& a, const f32x4& b,
                                                f16x8& hi, f16x8& lo) {
    unsigned h[4], l[4];
    #pragma unroll
    for (int p2 = 0; p2 < 2; ++p2) {
        float u0 = a[2 * p2], u1 = a[2 * p2 + 1];
        unsigned hp = pk(u0, u1);
        half2v hh = __builtin_bit_cast(half2v, hp);
        h[p2] = hp;
        l[p2] = pk(u0 - (float)hh[0], u1 - (float)hh[1]);
        float w0 = b[2 * p2], w1 = b[2 * p2 + 1];
        unsigned hq = pk(w0, w1);
        half2v hh2 = __builtin_bit_cast(half2v, hq);
        h[2 + p2] = hq;
        l[2 + p2] = pk(w0 - (float)hh2[0], w1 - (float)hh2[1]);
    }
    hi = __builtin_bit_cast(f16x8, (uint4v){h[0], h[1], h[2], h[3]});
    lo = __builtin_bit_cast(f16x8, (uint4v){l[0], l[1], l[2], l[3]});
}

// forward, single-f16 weight: D += W*Bh + W*Bl
static __device__ __forceinline__ f32x4 mfma2f(f16x8 w, f16x8 bh, f16x8 bl, f32x4 c) {
    c = __builtin_amdgcn_mfma_f32_16x16x32_f16(w, bh, c, 0, 0, 0);
    c = __builtin_amdgcn_mfma_f32_16x16x32_f16(w, bl, c, 0, 0, 0);
    return c;
}
// tangent, single-f16 both sides: one MFMA
static __device__ __forceinline__ f32x4 mfma1t(f16x8 w, f16x8 b, f32x4 c) {
    return __builtin_amdgcn_mfma_f32_16x16x32_f16(w, b, c, 0, 0, 0);
}

__global__ void __launch_bounds__(NTHR)
presdiv_kernel(const float* __restrict__ x,
               const float* __restrict__ W1, const float* __restrict__ b1,
               const float* __restrict__ W2, const float* __restrict__ b2,
               const float* __restrict__ W3, const float* __restrict__ b3,
               const float* __restrict__ W4,
               float* __restrict__ out, int N)
{
    const int lane = threadIdx.x & 63;
    const int wid  = threadIdx.x >> 6;
    const int n16  = lane & 15;        // sample-within-tile / MFMA col
    const int g    = lane >> 4;        // quad

    // ---- persistent weights (per lane), single f16 (RTN) ----
    f16x8 w2[2], w3[2];
    #pragma unroll
    for (int h = 0; h < 2; ++h) {
        #pragma unroll
        for (int j = 0; j < 8; ++j) {
            const int k2 = g * 8 + j;
            w2[h][j] = (_Float16)W2[k2 * 32 + 16 * h + n16];
            const int k3 = (j < 4) ? (4 * g + j) : (16 + 4 * g + (j - 4));
            w3[h][j] = (_Float16)W3[k3 * 32 + 16 * h + n16];
        }
    }
    // layer-1 rows + bias, vectorized in 2 chunks of 4 features
    f32x4 w1v[3][2], bb1v[2];
    #pragma unroll
    for (int c = 0; c < 2; ++c)
        #pragma unroll
        for (int i = 0; i < 4; ++i) {
            const int j = 4 * c + i;
            bb1v[c][i] = b1[g * 8 + j];
            #pragma unroll
            for (int d = 0; d < 3; ++d) w1v[d][c][i] = W1[d * 32 + g * 8 + j];
        }
    // C-layout biases + W4 column-vectors (k fixed, 4 rows per vector)
    f32x4 bb2v[2], bb3v[2], w4c[2][3];
    #pragma unroll
    for (int h = 0; h < 2; ++h)
        #pragma unroll
        for (int r = 0; r < 4; ++r) {
            const int row = 16 * h + 4 * g + r;
            bb2v[h][r] = b2[row];
            bb3v[h][r] = b3[row];
            #pragma unroll
            for (int k = 0; k < 3; ++k) w4c[h][k][r] = W4[row * 3 + k];
        }

    const int ntiles = (N + 15) >> 4;
    const int nwaves = gridDim.x * WAVES_PER_BLOCK;
    const f32x4 vzero = {0.f, 0.f, 0.f, 0.f};

    for (int tile = blockIdx.x * WAVES_PER_BLOCK + wid; tile < ntiles; tile += nwaves) {
        int s = tile * 16 + n16;
        if (s >= N) s = N - 1;
        const f32x4 X0 = splat4(x[3 * s + 0]);
        const f32x4 X1 = splat4(x[3 * s + 1]);
        const f32x4 X2 = splat4(x[3 * s + 2]);

        // ---- layer 1 (exact fp32, packed), directly in B-layout ----
        f32x4 vFv[2], v0v[2], v1v[2], v2v[2];
        #pragma unroll
        for (int c = 0; c < 2; ++c) {
            f32x4 z = __builtin_elementwise_fma(X0, w1v[0][c], bb1v[c]);
            z = __builtin_elementwise_fma(X1, w1v[1][c], z);
            z = __builtin_elementwise_fma(X2, w1v[2][c], z);
            f32x4 hv, sv;
            act_hs4(z, hv, sv);
            vFv[c] = hv;
            v0v[c] = sv * w1v[0][c];
            v1v[c] = sv * w1v[1][c];
            v2v[c] = sv * w1v[2][c];
        }

        // ---- layer 2 ----
        f32x4 aF[2], a0[2], a1[2], a2[2];
        aF[0] = bb2v[0]; aF[1] = bb2v[1];
        a0[0] = a0[1] = a1[0] = a1[1] = a2[0] = a2[1] = vzero;

        f16x8 bh, bl;
        fsplit8v(vFv[0], vFv[1], bh, bl);     // forward B: full split
        aF[0] = mfma2f(w2[0], bh, bl, aF[0]);
        aF[1] = mfma2f(w2[1], bh, bl, aF[1]);
        f16x8 tb = pack8v(v0v[0], v0v[1]);    // tangents: single f16
        a0[0] = mfma1t(w2[0], tb, a0[0]);
        a0[1] = mfma1t(w2[1], tb, a0[1]);
        tb = pack8v(v1v[0], v1v[1]);
        a1[0] = mfma1t(w2[0], tb, a1[0]);
        a1[1] = mfma1t(w2[1], tb, a1[1]);
        tb = pack8v(v2v[0], v2v[1]);
        a2[0] = mfma1t(w2[0], tb, a2[0]);
        a2[1] = mfma1t(w2[1], tb, a2[1]);

        // ---- boundary: act + diag-scale, packed, in C-layout ----
        #pragma unroll
        for (int h = 0; h < 2; ++h) {
            f32x4 hv, sv;
            act_hs4(aF[h], hv, sv);
            aF[h] = hv;                       // h2
            a0[h] *= sv;
            a1[h] *= sv;
            a2[h] *= sv;
        }

        // ---- layer 3: C-frags feed B directly (K-permuted weights) ----
        f32x4 zF[2], u0[2], u1[2], u2[2];
        zF[0] = bb3v[0]; zF[1] = bb3v[1];
        u0[0] = u0[1] = u1[0] = u1[1] = u2[0] = u2[1] = vzero;

        fsplit8v(aF[0], aF[1], bh, bl);
        zF[0] = mfma2f(w3[0], bh, bl, zF[0]);
        zF[1] = mfma2f(w3[1], bh, bl, zF[1]);
        tb = pack8v(a0[0], a0[1]);
        u0[0] = mfma1t(w3[0], tb, u0[0]);
        u0[1] = mfma1t(w3[1], tb, u0[1]);
        tb = pack8v(a1[0], a1[1]);
        u1[0] = mfma1t(w3[0], tb, u1[0]);
        u1[1] = mfma1t(w3[1], tb, u1[1]);
        tb = pack8v(a2[0], a2[1]);
        u2[0] = mfma1t(w3[0], tb, u2[0]);
        u2[1] = mfma1t(w3[1], tb, u2[1]);

        // ---- layer 4 + trace combine, packed across the 4 held rows ----
        // out0 = Σ t1*W4[:,0] + t2*W4[:,1]; out1 = Σ -t0*W4[:,0] + t2*W4[:,2];
        // out2 = Σ -t0*W4[:,1] - t1*W4[:,2]
        f32x4 O0 = vzero, O1 = vzero, O2 = vzero;
        #pragma unroll
        for (int h = 0; h < 2; ++h) {
            const f32x4 S  = sigmoid4(zF[h]);
            const f32x4 T0 = S * u0[h];
            const f32x4 T1 = S * u1[h];
            const f32x4 T2 = S * u2[h];
            O0 = __builtin_elementwise_fma(T1, w4c[h][0],
                 __builtin_elementwise_fma(T2, w4c[h][1], O0));
            O1 = __builtin_elementwise_fma(-T0, w4c[h][0],
                 __builtin_elementwise_fma(T2, w4c[h][2], O1));
            O2 = __builtin_elementwise_fma(-T0, w4c[h][1],
                 __builtin_elementwise_fma(-T1, w4c[h][2], O2));
        }
        float o0 = (O0[0] + O0[1]) + (O0[2] + O0[3]);
        float o1 = (O1[0] + O1[1]) + (O1[2] + O1[3]);
        float o2 = (O2[0] + O2[1]) + (O2[2] + O2[3]);

        o0 += __shfl_xor(o0, 16); o0 += __shfl_xor(o0, 32);
        o1 += __shfl_xor(o1, 16); o1 += __shfl_xor(o1, 32);
        o2 += __shfl_xor(o2, 16); o2 += __shfl_xor(o2, 32);

        if (g == 0) {
            out[3 * s + 0] = o0;
            out[3 * s + 1] = o1;
            out[3 * s + 2] = o2;
        }
    }
}

extern "C" void kernel_launch(void* const* d_in, const int* in_sizes, int n_in,
                              void* d_out, int out_size, void* d_ws, size_t ws_size,
                              hipStream_t stream)
{
    const float* x  = (const float*)d_in[0];
    const float* W1 = (const float*)d_in[1];
    const float* b1 = (const float*)d_in[2];
    const float* W2 = (const float*)d_in[3];
    const float* b2 = (const float*)d_in[4];
    const float* W3 = (const float*)d_in[5];
    const float* b3 = (const float*)d_in[6];
    const float* W4 = (const float*)d_in[7];
    // d_in[8] = b4 unused: constant offset cancels in the Jacobian.
    float* out = (float*)d_out;

    const int N = in_sizes[0] / 3;
    presdiv_kernel<<<4096, NTHR, 0, stream>>>(x, W1, b1, W2, b2, W3, b3, W4, out, N);
}